// Round 8
// baseline (214.726 us; speedup 1.0000x reference)
//
#include <hip/hip_runtime.h>

// SeesawLoss on MI355X.
// Inputs: d_in[0] = cls_score fp32 (8,16,512,512), d_in[1] = labels i32 (8,512,512),
//         d_in[2] = cum_samples fp32 (16). Output: d_out[0] = scalar loss fp32.
// ws layout (uint32 words):
//   [0 .. 255]     histogram, cacheline-spread: count for class c at word c*16
//   [256 .. 1279]  64 accumulator pairs, pair i at words 256 + i*16 (+0 nll, +1 mask)
//   [2048 ..]      per-pixel masked nll, 2M floats (8 MB)
//
// R3/R4/R7 (1px-dword/4px-float4/2px-float2, 16-32 waves/CU) all identical ->
// load-shape/TLP/MLP exhausted. Invariant: 16 loads/wave at exact 2^20-B stride
// (L2-set bits unchanged -> aliasing). R8: nontemporal loads (no L2 allocation;
// ext_vector_type satisfies the builtin, HIP_vector_type does not), multiplicative
// block permutation to spread active blocks across the address space, and an A/B
// split (per-pixel nll to ws, separate reducer) to bisect the timeline.

typedef float vf4 __attribute__((ext_vector_type(4)));
typedef int   vi4 __attribute__((ext_vector_type(4)));

constexpr int   kC      = 16;
constexpr int   kHW     = 512 * 512;               // 2^18
constexpr float kP      = 0.8f;                    // mitigation exponent
constexpr float kLogEps = -4.605170185988091f;     // ln(0.01)
constexpr int   kNAcc   = 64;                      // spread accumulator pairs
constexpr int   kNllOff = 2048;                    // word offset of nll array in ws

__global__ __launch_bounds__(256) void init_ws_k(unsigned int* ws) {
    for (int i = threadIdx.x; i < 256 + kNAcc * 16; i += 256) ws[i] = 0u;
}

// 512 blocks; block b covers contiguous 16 KB of labels (1024 int4). 4 independent
// unrolled int4 loads/thread; register counters; cacheline-spread atomics.
__global__ __launch_bounds__(256) void hist_k(const int4* __restrict__ lab4,
                                              unsigned int* __restrict__ histp) {
    int base = blockIdx.x * 1024 + threadIdx.x;
    int4 v[4];
    #pragma unroll
    for (int j = 0; j < 4; ++j) v[j] = lab4[base + j * 256];
    int cnt[16];
    #pragma unroll
    for (int c = 0; c < 16; ++c) cnt[c] = 0;
    #pragma unroll
    for (int j = 0; j < 4; ++j) {
        #pragma unroll
        for (int c = 0; c < 16; ++c)
            cnt[c] += (v[j].x == c) + (v[j].y == c) + (v[j].z == c) + (v[j].w == c);
    }
    #pragma unroll
    for (int c = 0; c < 16; ++c) {
        int x = cnt[c];
        #pragma unroll
        for (int off = 32; off > 0; off >>= 1) x += __shfl_down(x, off);
        cnt[c] = x;
    }
    __shared__ unsigned int sh[4 * 16];
    int wave = threadIdx.x >> 6, lane = threadIdx.x & 63;
    if (lane == 0) {
        #pragma unroll
        for (int c = 0; c < 16; ++c) sh[wave * 16 + c] = (unsigned)cnt[c];
    }
    __syncthreads();
    int t = threadIdx.x;
    if (t < 16)   // per-class slots 64 B apart
        atomicAdd(&histp[t * 16], sh[t] + sh[16 + t] + sh[32 + t] + sh[48 + t]);
}

// Phase A: 4 px/thread, nontemporal float4 channel loads, permuted block order,
// per-pixel masked nll written to ws (no reduction here).
__global__ __launch_bounds__(256, 4) void seesawA_k(const float* __restrict__ cls,
                                                    const int*   __restrict__ labels,
                                                    const float* __restrict__ cum_in,
                                                    const unsigned int* __restrict__ histp,
                                                    float* __restrict__ nll_out) {
    __shared__ float s_plog[16];
    int t = threadIdx.x;
    if (t < 16) {
        float cc = fmaxf((float)histp[t * 16] + cum_in[t], 1.0f);  // clip(cum, 1, inf)
        s_plog[t] = kP * __logf(cc);
    }
    __syncthreads();

    int bid = (int)((blockIdx.x * 997u) & 2047u);  // odd multiplier: bijection mod 2048
    long long m0 = (long long)(bid * 256 + t) * 4; // first of 4 pixels
    int b  = (int)(m0 >> 18);                      // 4 | 2^18: no batch-crossing
    int hw = (int)(m0 & (kHW - 1));
    const float* pbase = cls + (long long)b * kC * kHW + hw;

    vf4 lv[16];
    #pragma unroll
    for (int c = 0; c < 16; ++c)
        lv[c] = __builtin_nontemporal_load((const vf4*)(pbase + (long long)c * kHW));
    const vi4 lab4 = __builtin_nontemporal_load((const vi4*)(labels + m0));

    float pl[16];
    #pragma unroll
    for (int c = 0; c < 16; ++c) pl[c] = s_plog[c];            // wave-uniform broadcast

    int labs[4] = {lab4[0], lab4[1], lab4[2], lab4[3]};
    vf4 nll4;

    #pragma unroll
    for (int p = 0; p < 4; ++p) {
        float l[16];
        #pragma unroll
        for (int c = 0; c < 16; ++c) l[c] = lv[c][p];
        int lab = labs[p];

        float m1 = l[0];
        float llab = l[0];                                     // select chain, no dyn index
        #pragma unroll
        for (int c = 1; c < 16; ++c) {
            m1 = fmaxf(m1, l[c]);
            if (c == lab) llab = l[c];
        }
        float s = 0.0f;
        #pragma unroll
        for (int c = 0; c < 16; ++c) s += __expf(l[c] - m1);
        // log(score_mat[c]) = l[c] - K, K = max(llab, m1 + log s + log EPS)
        float K = fmaxf(llab, m1 + __logf(s) + kLogEps);
        float plab = s_plog[lab];                              // LDS gather

        float m2 = -3.0e38f;
        #pragma unroll
        for (int c = 0; c < 16; ++c) {
            // adj = l + log(mit) + log(comp); both clamp to 0 at c==lab -> adj==llab
            float a = l[c] + fminf(0.0f, pl[c] - plab)
                           + fmaxf(0.0f, 2.0f * (l[c] - K));
            l[c] = a;
            m2 = fmaxf(m2, a);
        }
        float s2 = 0.0f;
        #pragma unroll
        for (int c = 0; c < 16; ++c) s2 += __expf(l[c] - m2);
        float nll = m2 + __logf(s2) - llab;                    // -log_softmax(adj)[lab]
        nll4[p] = (lab != 0) ? nll : 0.0f;                     // ignore_index = 0
    }
    __builtin_nontemporal_store(nll4, (vf4*)(nll_out + m0));
}

// Phase B: sum masked nll + recount mask from labels; both linear streams.
__global__ __launch_bounds__(256) void reduceB_k(const float* __restrict__ nll,
                                                 const int*   __restrict__ labels,
                                                 float* __restrict__ ws) {
    long long m0 = (long long)(blockIdx.x * 256 + threadIdx.x) * 4;
    const vf4 n4 = *(const vf4*)(nll + m0);
    const vi4 l4 = *(const vi4*)(labels + m0);
    float lsum = n4[0] + n4[1] + n4[2] + n4[3];
    float lcnt = (float)((l4[0] != 0) + (l4[1] != 0) + (l4[2] != 0) + (l4[3] != 0));
    #pragma unroll
    for (int off = 32; off > 0; off >>= 1) {
        lsum += __shfl_down(lsum, off);
        lcnt += __shfl_down(lcnt, off);
    }
    __shared__ float s_red[8];
    int wave = threadIdx.x >> 6, lane = threadIdx.x & 63;
    if (lane == 0) { s_red[wave] = lsum; s_red[4 + wave] = lcnt; }
    __syncthreads();
    if (threadIdx.x == 0) {
        float* pair = ws + 256 + (blockIdx.x & (kNAcc - 1)) * 16;   // 64 B-spread pairs
        atomicAdd(&pair[0], s_red[0] + s_red[1] + s_red[2] + s_red[3]);
        atomicAdd(&pair[1], s_red[4] + s_red[5] + s_red[6] + s_red[7]);
    }
}

__global__ void final_k(const float* __restrict__ ws, float* __restrict__ out) {
    int t = threadIdx.x;                           // one wave
    float a = (t < kNAcc) ? ws[256 + t * 16]     : 0.0f;
    float b = (t < kNAcc) ? ws[256 + t * 16 + 1] : 0.0f;
    #pragma unroll
    for (int off = 32; off > 0; off >>= 1) {
        a += __shfl_down(a, off);
        b += __shfl_down(b, off);
    }
    if (t == 0) out[0] = a / b;
}

extern "C" void kernel_launch(void* const* d_in, const int* in_sizes, int n_in,
                              void* d_out, int out_size, void* d_ws, size_t ws_size,
                              hipStream_t stream) {
    const float* cls    = (const float*)d_in[0];
    const int*   labels = (const int*)d_in[1];
    const float* cum_in = (const float*)d_in[2];
    float* out = (float*)d_out;
    unsigned int* ws = (unsigned int*)d_ws;
    float* nll = (float*)ws + kNllOff;

    int M  = in_sizes[1];        // 2,097,152 pixels
    int n4 = M / 4;

    init_ws_k<<<1, 256, 0, stream>>>(ws);
    hist_k<<<n4 / 1024, 256, 0, stream>>>((const int4*)labels, ws);
    seesawA_k<<<M / 1024, 256, 0, stream>>>(cls, labels, cum_in, ws, nll);
    reduceB_k<<<M / 1024, 256, 0, stream>>>(nll, labels, (float*)ws);
    final_k<<<1, 64, 0, stream>>>((const float*)ws, out);
}